// Round 6
// baseline (2337.317 us; speedup 1.0000x reference)
//
#include <hip/hip_runtime.h>
#include <stdint.h>

#define T_STEPS 100
#define BATCH   256
#define NIN     784
#define NHID    512
#define NOUT    10

// ===========================================================================
// NUMERICS CONTRACT (validated PASS in R5 — do not break):
//   * gemm1: fp32, per-element single-accumulator fmaf chain, k ascending,
//     panel folds (one __fadd_rn each) at k=384 and k=768 (OpenBLAS kc=384),
//     final (tot+acc) then rounded +bias.  Tile/LDS shape is free; the
//     per-element op sequence is NOT.
//   * gemm2: f64 accumulation of fp32 products, +b2 in f64, single rounding.
//   * recurrences: fp32 _rn ops, ((0.95*mem + cur) - rst), no contraction;
//     spike/reset = (mem > 1.0f).
// ===========================================================================

// ---------------------------------------------------------------------------
// GEMM1: M=25600, N=512, K=784.  BM=128, BN=64, BK=16, 256 thr, 8x4 micro.
// Double-buffered LDS, single barrier per K-iteration, prefetch-ahead global
// loads. acc+tot = 64 VGPRs -> 3 waves/SIMD (launch_bounds 256,3).
// ---------------------------------------------------------------------------
#define BM 128
#define BN 64
#define BK 16

__global__ __launch_bounds__(256, 3) void gemm1_kernel(
    const float* __restrict__ X, const float* __restrict__ W,
    const float* __restrict__ bias, float* __restrict__ C,
    int M, int N, int K)
{
    __shared__ float As[2][BK][BM + 4];   // 2 x 8448 B
    __shared__ float Bs[2][BK][BN + 4];   // 2 x 4352 B

    const int tid = threadIdx.x;
    const int bm  = blockIdx.x * BM;
    const int bn  = blockIdx.y * BN;

    // staging mapping
    const int lr = tid >> 1;            // 0..127  A row
    const int lk = (tid & 1) * 8;       // 0 or 8  A k-offset (2 float4)
    const int br = tid >> 2;            // 0..63   B row
    const int bk = (tid & 3) * 4;       // 0,4,8,12 B k-offset (1 float4)

    // compute mapping: 16 x 16 threads, micro 8 (m) x 4 (n)
    const int tm = (tid >> 4) * 8;      // 0..120
    const int tn = (tid & 15) * 4;      // 0..60

    float acc[8][4], tot[8][4];
    #pragma unroll
    for (int i = 0; i < 8; ++i)
        #pragma unroll
        for (int j = 0; j < 4; ++j) { acc[i][j] = 0.f; tot[i][j] = 0.f; }

    const float* Xp = X + (size_t)(bm + lr) * K + lk;
    const float* Wp = W + (size_t)(bn + br) * K + bk;

    // prologue: stage iter 0 into buffer 0
    float4 pa0 = *(const float4*)(Xp + 0);
    float4 pa1 = *(const float4*)(Xp + 4);
    float4 pb0 = *(const float4*)(Wp + 0);
    {
        As[0][lk+0][lr] = pa0.x; As[0][lk+1][lr] = pa0.y;
        As[0][lk+2][lr] = pa0.z; As[0][lk+3][lr] = pa0.w;
        As[0][lk+4][lr] = pa1.x; As[0][lk+5][lr] = pa1.y;
        As[0][lk+6][lr] = pa1.z; As[0][lk+7][lr] = pa1.w;
        Bs[0][bk+0][br] = pb0.x; Bs[0][bk+1][br] = pb0.y;
        Bs[0][bk+2][br] = pb0.z; Bs[0][bk+3][br] = pb0.w;
    }

    const int NITER = K / BK;   // 49
    for (int it = 0; it < NITER; ++it) {
        const int cur = it & 1;
        __syncthreads();   // buf[cur] writes visible; prev reads of buf[cur^1] done

        // prefetch next tile (latency hidden under the 16-kk compute below)
        if (it + 1 < NITER) {
            const int k0 = (it + 1) * BK;
            pa0 = *(const float4*)(Xp + k0);
            pa1 = *(const float4*)(Xp + k0 + 4);
            pb0 = *(const float4*)(Wp + k0);
        }

        #pragma unroll
        for (int kk = 0; kk < BK; ++kk) {   // k ascending within panel
            float4 av0 = *(const float4*)&As[cur][kk][tm];
            float4 av1 = *(const float4*)&As[cur][kk][tm + 4];
            float4 bv  = *(const float4*)&Bs[cur][kk][tn];
            float a[8] = {av0.x, av0.y, av0.z, av0.w, av1.x, av1.y, av1.z, av1.w};
            float b[4] = {bv.x, bv.y, bv.z, bv.w};
            #pragma unroll
            for (int i = 0; i < 8; ++i)
                #pragma unroll
                for (int j = 0; j < 4; ++j)
                    acc[i][j] = fmaf(a[i], b[j], acc[i][j]);
        }

        // OpenBLAS kc=384 panel boundary: after k=383 (it=23) and k=767 (it=47)
        if (it == 23 || it == 47) {
            #pragma unroll
            for (int i = 0; i < 8; ++i)
                #pragma unroll
                for (int j = 0; j < 4; ++j) {
                    tot[i][j] = __fadd_rn(tot[i][j], acc[i][j]);
                    acc[i][j] = 0.f;
                }
        }

        // write next tile into the other buffer (safe: one barrier ago all
        // waves finished reading it; visibility via next iteration's barrier)
        if (it + 1 < NITER) {
            const int nxt = cur ^ 1;
            As[nxt][lk+0][lr] = pa0.x; As[nxt][lk+1][lr] = pa0.y;
            As[nxt][lk+2][lr] = pa0.z; As[nxt][lk+3][lr] = pa0.w;
            As[nxt][lk+4][lr] = pa1.x; As[nxt][lk+5][lr] = pa1.y;
            As[nxt][lk+6][lr] = pa1.z; As[nxt][lk+7][lr] = pa1.w;
            Bs[nxt][bk+0][br] = pb0.x; Bs[nxt][bk+1][br] = pb0.y;
            Bs[nxt][bk+2][br] = pb0.z; Bs[nxt][bk+3][br] = pb0.w;
        }
    }

    #pragma unroll
    for (int i = 0; i < 8; ++i) {
        size_t row = (size_t)(bm + tm + i) * N + bn + tn;
        float4 o;
        o.x = __fadd_rn(__fadd_rn(tot[i][0], acc[i][0]), bias[bn + tn + 0]);
        o.y = __fadd_rn(__fadd_rn(tot[i][1], acc[i][1]), bias[bn + tn + 1]);
        o.z = __fadd_rn(__fadd_rn(tot[i][2], acc[i][2]), bias[bn + tn + 2]);
        o.w = __fadd_rn(__fadd_rn(tot[i][3], acc[i][3]), bias[bn + tn + 3]);
        *(float4*)&C[row] = o;
    }
}

// ---------------------------------------------------------------------------
// Hidden Leaky recurrence (fp32 _rn), float4-vectorized: each thread owns 4
// consecutive (b,h) chains. In place: mem_io holds cur1 on entry, mem1 on
// exit. Chains are independent -> bit-exact per element.
// ---------------------------------------------------------------------------
__global__ __launch_bounds__(256) void leaky_hidden_kernel(
    float* __restrict__ mem_io, float* __restrict__ spk_out)
{
    const int idx = blockIdx.x * blockDim.x + threadIdx.x;  // 0..32767
    float4 mem = {0.f, 0.f, 0.f, 0.f};
    size_t off = (size_t)idx * 4;
    #pragma unroll 2
    for (int t = 0; t < T_STEPS; ++t, off += (size_t)BATCH * NHID) {
        float4 cur = *(const float4*)(mem_io + off);
        float4 spk;
        mem.x = __fsub_rn(__fadd_rn(__fmul_rn(0.95f, mem.x), cur.x), (mem.x > 1.0f) ? 1.0f : 0.0f);
        mem.y = __fsub_rn(__fadd_rn(__fmul_rn(0.95f, mem.y), cur.y), (mem.y > 1.0f) ? 1.0f : 0.0f);
        mem.z = __fsub_rn(__fadd_rn(__fmul_rn(0.95f, mem.z), cur.z), (mem.z > 1.0f) ? 1.0f : 0.0f);
        mem.w = __fsub_rn(__fadd_rn(__fmul_rn(0.95f, mem.w), cur.w), (mem.w > 1.0f) ? 1.0f : 0.0f);
        spk.x = (mem.x > 1.0f) ? 1.0f : 0.0f;
        spk.y = (mem.y > 1.0f) ? 1.0f : 0.0f;
        spk.z = (mem.z > 1.0f) ? 1.0f : 0.0f;
        spk.w = (mem.w > 1.0f) ? 1.0f : 0.0f;
        *(float4*)(spk_out + off) = spk;
        *(float4*)(mem_io + off)  = mem;
    }
}

// ---------------------------------------------------------------------------
// GEMM2: cur2[m][o] = fl32( f64( sum_k spk1[m][k]*W2[o][k] + b2[o] ) )
// W2 (20 KB) staged in LDS. Block = 320 threads = 32 rows x 10 outputs.
// ---------------------------------------------------------------------------
#define G2_ROWS 32

__global__ __launch_bounds__(320) void gemm2_f64(
    const float* __restrict__ spk1, const float* __restrict__ W2,
    const float* __restrict__ b2, float* __restrict__ cur2)
{
    __shared__ float w2s[NOUT * NHID];  // 20 KB
    const int tid = threadIdx.x;
    for (int i = tid; i < NOUT * NHID; i += 320) w2s[i] = W2[i];
    __syncthreads();

    const int r = tid / NOUT;   // 0..31
    const int o = tid % NOUT;   // 0..9
    const size_t m = (size_t)blockIdx.x * G2_ROWS + r;
    const float* row = spk1 + m * NHID;
    const float* w   = w2s + o * NHID;
    double dot = 0.0;
    #pragma unroll 4
    for (int k = 0; k < NHID; k += 4) {
        float4 s  = *(const float4*)(row + k);
        float4 wv = *(const float4*)(w + k);
        dot = fma((double)s.x, (double)wv.x, dot);
        dot = fma((double)s.y, (double)wv.y, dot);
        dot = fma((double)s.z, (double)wv.z, dot);
        dot = fma((double)s.w, (double)wv.w, dot);
    }
    cur2[m * NOUT + o] = (float)(dot + (double)b2[o]);   // coalesced
}

// ---------------------------------------------------------------------------
// Output Leaky recurrence (fp32 _rn): one thread per (b,o) chain (2560).
// Software-pipelined cur2 loads.
// ---------------------------------------------------------------------------
__global__ __launch_bounds__(256) void leaky_out_kernel(
    const float* __restrict__ cur2, float* __restrict__ spk2,
    float* __restrict__ mem2)
{
    const int idx = blockIdx.x * blockDim.x + threadIdx.x;
    if (idx >= BATCH * NOUT) return;
    const int STRIDE = BATCH * NOUT;

    float buf[8];
    #pragma unroll
    for (int i = 0; i < 8; ++i) buf[i] = cur2[(size_t)i * STRIDE + idx];

    float mem = 0.f;
    #pragma unroll 4
    for (int t = 0; t < T_STEPS; ++t) {
        float cur = buf[t & 7];
        int tn = t + 8;
        if (tn < T_STEPS) buf[t & 7] = cur2[(size_t)tn * STRIDE + idx];
        float rst = (mem > 1.0f) ? 1.0f : 0.0f;
        mem = __fsub_rn(__fadd_rn(__fmul_rn(0.95f, mem), cur), rst);
        size_t off = (size_t)t * STRIDE + idx;
        spk2[off] = (mem > 1.0f) ? 1.0f : 0.0f;
        mem2[off] = mem;
    }
}

// ---------------------------------------------------------------------------
extern "C" void kernel_launch(void* const* d_in, const int* in_sizes, int n_in,
                              void* d_out, int out_size, void* d_ws, size_t ws_size,
                              hipStream_t stream) {
    const float* x  = (const float*)d_in[0];   // (100, 256, 784)
    const float* w1 = (const float*)d_in[1];   // (512, 784)
    const float* b1 = (const float*)d_in[2];   // (512,)
    const float* w2 = (const float*)d_in[3];   // (10, 512)
    const float* b2 = (const float*)d_in[4];   // (10,)

    float* out = (float*)d_out;
    // Output tuple order: (cur2, spk2, spk1, mem2, mem1), each stacked over T.
    float* cur2_out = out;                       // 256000
    float* spk2_out = out + 256000;              // 256000
    float* spk1_out = out + 512000;              // 13107200
    float* mem2_out = out + 13619200;            // 256000
    float* mem1_out = out + 13875200;            // 13107200

    const int M = T_STEPS * BATCH;               // 25600

    // 1) cur1 = X @ W1^T + b1 (fp32, kc=384-blocked fma chains) -> mem1 region
    dim3 g1(M / BM, NHID / BN);                  // (200, 8)
    gemm1_kernel<<<g1, 256, 0, stream>>>(x, w1, b1, mem1_out, M, NHID, NIN);

    // 2) hidden Leaky chains (fp32 _rn, float4): cur1 -> (mem1 in place, spk1)
    leaky_hidden_kernel<<<(BATCH * NHID / 4) / 256, 256, 0, stream>>>(mem1_out, spk1_out);

    // 3) cur2 = spk1 @ W2^T + b2 (f64 acc -> fp32)
    gemm2_f64<<<M / G2_ROWS, 320, 0, stream>>>(spk1_out, w2, b2, cur2_out);

    // 4) output Leaky chains (fp32 _rn): cur2 -> (spk2, mem2)
    leaky_out_kernel<<<(BATCH * NOUT + 255) / 256, 256, 0, stream>>>(
        cur2_out, spk2_out, mem2_out);
}

// Round 7
// 631.996 us; speedup vs baseline: 3.6983x; 3.6983x over previous
//
#include <hip/hip_runtime.h>
#include <stdint.h>

#define T_STEPS 100
#define BATCH   256
#define NIN     784
#define NHID    512
#define NOUT    10

// ===========================================================================
// NUMERICS CONTRACT (validated PASS in R5/R6 — do not break):
//   * gemm1: fp32, per-element single-accumulator fmaf chain, k ascending,
//     panel folds (one __fadd_rn each) at k=384 and k=768 (OpenBLAS kc=384),
//     final (tot+acc) then rounded +bias.  Tile/LDS shape is free; the
//     per-element op sequence is NOT.
//   * gemm2: f64 accumulation of fp32 products, +b2 in f64, single rounding.
//   * recurrences: fp32 _rn ops, ((0.95*mem + cur) - rst), no contraction;
//     spike/reset = (mem > 1.0f).
// PERF JOURNAL:
//   * R5 (single-buffer, 8x8, 212 VGPR): 570 us, VALUBusy 36%, latency-bound.
//   * R6 (+dbuf/prefetch/8x4 BUT __launch_bounds__(256,3)): VGPR clamped to
//     84 -> acc/tot spilled to scratch -> 9.5 GB HBM traffic, 2144 us.
//     NEVER use the min-waves arg here; control register demand instead.
// ===========================================================================

// ---------------------------------------------------------------------------
// GEMM1: M=25600, N=512, K=784.  BM=128, BN=64, BK=16, 256 thr, 8x4 micro.
// Double-buffered LDS, single barrier per K-iteration, prefetch-ahead global
// loads. acc+tot = 64 VGPRs; total demand ~150 -> 3 waves/SIMD naturally.
// ---------------------------------------------------------------------------
#define BM 128
#define BN 64
#define BK 16

__global__ __launch_bounds__(256) void gemm1_kernel(
    const float* __restrict__ X, const float* __restrict__ W,
    const float* __restrict__ bias, float* __restrict__ C,
    int M, int N, int K)
{
    __shared__ float As[2][BK][BM + 4];   // 2 x 8448 B
    __shared__ float Bs[2][BK][BN + 4];   // 2 x 4352 B

    const int tid = threadIdx.x;
    const int bm  = blockIdx.x * BM;
    const int bn  = blockIdx.y * BN;

    // staging mapping
    const int lr = tid >> 1;            // 0..127  A row
    const int lk = (tid & 1) * 8;       // 0 or 8  A k-offset (2 float4)
    const int br = tid >> 2;            // 0..63   B row
    const int bk = (tid & 3) * 4;       // 0,4,8,12 B k-offset (1 float4)

    // compute mapping: 16 x 16 threads, micro 8 (m) x 4 (n)
    const int tm = (tid >> 4) * 8;      // 0..120
    const int tn = (tid & 15) * 4;      // 0..60

    float acc[8][4], tot[8][4];
    #pragma unroll
    for (int i = 0; i < 8; ++i)
        #pragma unroll
        for (int j = 0; j < 4; ++j) { acc[i][j] = 0.f; tot[i][j] = 0.f; }

    const float* Xp = X + (size_t)(bm + lr) * K + lk;
    const float* Wp = W + (size_t)(bn + br) * K + bk;

    // prologue: stage iter 0 into buffer 0
    float4 pa0 = *(const float4*)(Xp + 0);
    float4 pa1 = *(const float4*)(Xp + 4);
    float4 pb0 = *(const float4*)(Wp + 0);
    {
        As[0][lk+0][lr] = pa0.x; As[0][lk+1][lr] = pa0.y;
        As[0][lk+2][lr] = pa0.z; As[0][lk+3][lr] = pa0.w;
        As[0][lk+4][lr] = pa1.x; As[0][lk+5][lr] = pa1.y;
        As[0][lk+6][lr] = pa1.z; As[0][lk+7][lr] = pa1.w;
        Bs[0][bk+0][br] = pb0.x; Bs[0][bk+1][br] = pb0.y;
        Bs[0][bk+2][br] = pb0.z; Bs[0][bk+3][br] = pb0.w;
    }

    const int NITER = K / BK;   // 49
    for (int it = 0; it < NITER; ++it) {
        const int cur = it & 1;
        __syncthreads();   // buf[cur] writes visible; prior reads of buf[cur^1] done

        // prefetch next tile (latency hidden under the 16-kk compute below)
        if (it + 1 < NITER) {
            const int k0 = (it + 1) * BK;
            pa0 = *(const float4*)(Xp + k0);
            pa1 = *(const float4*)(Xp + k0 + 4);
            pb0 = *(const float4*)(Wp + k0);
        }

        #pragma unroll
        for (int kk = 0; kk < BK; ++kk) {   // k ascending within panel
            float4 av0 = *(const float4*)&As[cur][kk][tm];
            float4 av1 = *(const float4*)&As[cur][kk][tm + 4];
            float4 bv  = *(const float4*)&Bs[cur][kk][tn];
            float a[8] = {av0.x, av0.y, av0.z, av0.w, av1.x, av1.y, av1.z, av1.w};
            float b[4] = {bv.x, bv.y, bv.z, bv.w};
            #pragma unroll
            for (int i = 0; i < 8; ++i)
                #pragma unroll
                for (int j = 0; j < 4; ++j)
                    acc[i][j] = fmaf(a[i], b[j], acc[i][j]);
        }

        // OpenBLAS kc=384 panel boundary: after k=383 (it=23) and k=767 (it=47)
        if (it == 23 || it == 47) {
            #pragma unroll
            for (int i = 0; i < 8; ++i)
                #pragma unroll
                for (int j = 0; j < 4; ++j) {
                    tot[i][j] = __fadd_rn(tot[i][j], acc[i][j]);
                    acc[i][j] = 0.f;
                }
        }

        // write next tile into the other buffer (safe: the barrier above
        // separates iter i-1's reads of this buffer from these writes)
        if (it + 1 < NITER) {
            const int nxt = cur ^ 1;
            As[nxt][lk+0][lr] = pa0.x; As[nxt][lk+1][lr] = pa0.y;
            As[nxt][lk+2][lr] = pa0.z; As[nxt][lk+3][lr] = pa0.w;
            As[nxt][lk+4][lr] = pa1.x; As[nxt][lk+5][lr] = pa1.y;
            As[nxt][lk+6][lr] = pa1.z; As[nxt][lk+7][lr] = pa1.w;
            Bs[nxt][bk+0][br] = pb0.x; Bs[nxt][bk+1][br] = pb0.y;
            Bs[nxt][bk+2][br] = pb0.z; Bs[nxt][bk+3][br] = pb0.w;
        }
    }

    #pragma unroll
    for (int i = 0; i < 8; ++i) {
        size_t row = (size_t)(bm + tm + i) * N + bn + tn;
        float4 o;
        o.x = __fadd_rn(__fadd_rn(tot[i][0], acc[i][0]), bias[bn + tn + 0]);
        o.y = __fadd_rn(__fadd_rn(tot[i][1], acc[i][1]), bias[bn + tn + 1]);
        o.z = __fadd_rn(__fadd_rn(tot[i][2], acc[i][2]), bias[bn + tn + 2]);
        o.w = __fadd_rn(__fadd_rn(tot[i][3], acc[i][3]), bias[bn + tn + 3]);
        *(float4*)&C[row] = o;
    }
}

// ---------------------------------------------------------------------------
// Hidden Leaky recurrence (fp32 _rn), float4-vectorized: each thread owns 4
// consecutive (b,h) chains. In place: mem_io holds cur1 on entry, mem1 on
// exit. Chains are independent -> bit-exact per element.
// ---------------------------------------------------------------------------
__global__ __launch_bounds__(256) void leaky_hidden_kernel(
    float* __restrict__ mem_io, float* __restrict__ spk_out)
{
    const int idx = blockIdx.x * blockDim.x + threadIdx.x;  // 0..32767
    float4 mem = {0.f, 0.f, 0.f, 0.f};
    size_t off = (size_t)idx * 4;
    #pragma unroll 2
    for (int t = 0; t < T_STEPS; ++t, off += (size_t)BATCH * NHID) {
        float4 cur = *(const float4*)(mem_io + off);
        float4 spk;
        mem.x = __fsub_rn(__fadd_rn(__fmul_rn(0.95f, mem.x), cur.x), (mem.x > 1.0f) ? 1.0f : 0.0f);
        mem.y = __fsub_rn(__fadd_rn(__fmul_rn(0.95f, mem.y), cur.y), (mem.y > 1.0f) ? 1.0f : 0.0f);
        mem.z = __fsub_rn(__fadd_rn(__fmul_rn(0.95f, mem.z), cur.z), (mem.z > 1.0f) ? 1.0f : 0.0f);
        mem.w = __fsub_rn(__fadd_rn(__fmul_rn(0.95f, mem.w), cur.w), (mem.w > 1.0f) ? 1.0f : 0.0f);
        spk.x = (mem.x > 1.0f) ? 1.0f : 0.0f;
        spk.y = (mem.y > 1.0f) ? 1.0f : 0.0f;
        spk.z = (mem.z > 1.0f) ? 1.0f : 0.0f;
        spk.w = (mem.w > 1.0f) ? 1.0f : 0.0f;
        *(float4*)(spk_out + off) = spk;
        *(float4*)(mem_io + off)  = mem;
    }
}

// ---------------------------------------------------------------------------
// GEMM2: cur2[m][o] = fl32( f64( sum_k spk1[m][k]*W2[o][k] + b2[o] ) )
// W2 (20 KB) staged in LDS. Block = 320 threads = 32 rows x 10 outputs.
// ---------------------------------------------------------------------------
#define G2_ROWS 32

__global__ __launch_bounds__(320) void gemm2_f64(
    const float* __restrict__ spk1, const float* __restrict__ W2,
    const float* __restrict__ b2, float* __restrict__ cur2)
{
    __shared__ float w2s[NOUT * NHID];  // 20 KB
    const int tid = threadIdx.x;
    for (int i = tid; i < NOUT * NHID; i += 320) w2s[i] = W2[i];
    __syncthreads();

    const int r = tid / NOUT;   // 0..31
    const int o = tid % NOUT;   // 0..9
    const size_t m = (size_t)blockIdx.x * G2_ROWS + r;
    const float* row = spk1 + m * NHID;
    const float* w   = w2s + o * NHID;
    double dot = 0.0;
    #pragma unroll 4
    for (int k = 0; k < NHID; k += 4) {
        float4 s  = *(const float4*)(row + k);
        float4 wv = *(const float4*)(w + k);
        dot = fma((double)s.x, (double)wv.x, dot);
        dot = fma((double)s.y, (double)wv.y, dot);
        dot = fma((double)s.z, (double)wv.z, dot);
        dot = fma((double)s.w, (double)wv.w, dot);
    }
    cur2[m * NOUT + o] = (float)(dot + (double)b2[o]);   // coalesced
}

// ---------------------------------------------------------------------------
// Output Leaky recurrence (fp32 _rn): one thread per (b,o) chain (2560).
// Software-pipelined cur2 loads.
// ---------------------------------------------------------------------------
__global__ __launch_bounds__(256) void leaky_out_kernel(
    const float* __restrict__ cur2, float* __restrict__ spk2,
    float* __restrict__ mem2)
{
    const int idx = blockIdx.x * blockDim.x + threadIdx.x;
    if (idx >= BATCH * NOUT) return;
    const int STRIDE = BATCH * NOUT;

    float buf[8];
    #pragma unroll
    for (int i = 0; i < 8; ++i) buf[i] = cur2[(size_t)i * STRIDE + idx];

    float mem = 0.f;
    #pragma unroll 4
    for (int t = 0; t < T_STEPS; ++t) {
        float cur = buf[t & 7];
        int tn = t + 8;
        if (tn < T_STEPS) buf[t & 7] = cur2[(size_t)tn * STRIDE + idx];
        float rst = (mem > 1.0f) ? 1.0f : 0.0f;
        mem = __fsub_rn(__fadd_rn(__fmul_rn(0.95f, mem), cur), rst);
        size_t off = (size_t)t * STRIDE + idx;
        spk2[off] = (mem > 1.0f) ? 1.0f : 0.0f;
        mem2[off] = mem;
    }
}

// ---------------------------------------------------------------------------
extern "C" void kernel_launch(void* const* d_in, const int* in_sizes, int n_in,
                              void* d_out, int out_size, void* d_ws, size_t ws_size,
                              hipStream_t stream) {
    const float* x  = (const float*)d_in[0];   // (100, 256, 784)
    const float* w1 = (const float*)d_in[1];   // (512, 784)
    const float* b1 = (const float*)d_in[2];   // (512,)
    const float* w2 = (const float*)d_in[3];   // (10, 512)
    const float* b2 = (const float*)d_in[4];   // (10,)

    float* out = (float*)d_out;
    // Output tuple order: (cur2, spk2, spk1, mem2, mem1), each stacked over T.
    float* cur2_out = out;                       // 256000
    float* spk2_out = out + 256000;              // 256000
    float* spk1_out = out + 512000;              // 13107200
    float* mem2_out = out + 13619200;            // 256000
    float* mem1_out = out + 13875200;            // 13107200

    const int M = T_STEPS * BATCH;               // 25600

    // 1) cur1 = X @ W1^T + b1 (fp32, kc=384-blocked fma chains) -> mem1 region
    dim3 g1(M / BM, NHID / BN);                  // (200, 8)
    gemm1_kernel<<<g1, 256, 0, stream>>>(x, w1, b1, mem1_out, M, NHID, NIN);

    // 2) hidden Leaky chains (fp32 _rn, float4): cur1 -> (mem1 in place, spk1)
    leaky_hidden_kernel<<<(BATCH * NHID / 4) / 256, 256, 0, stream>>>(mem1_out, spk1_out);

    // 3) cur2 = spk1 @ W2^T + b2 (f64 acc -> fp32)
    gemm2_f64<<<M / G2_ROWS, 320, 0, stream>>>(spk1_out, w2, b2, cur2_out);

    // 4) output Leaky chains (fp32 _rn): cur2 -> (spk2, mem2)
    leaky_out_kernel<<<(BATCH * NOUT + 255) / 256, 256, 0, stream>>>(
        cur2_out, spk2_out, mem2_out);
}

// Round 8
// 574.031 us; speedup vs baseline: 4.0718x; 1.1010x over previous
//
#include <hip/hip_runtime.h>
#include <stdint.h>

#define T_STEPS 100
#define BATCH   256
#define NIN     784
#define NHID    512
#define NOUT    10

// ===========================================================================
// NUMERICS CONTRACT (validated PASS R5/R6/R7 — do not break):
//   * gemm1: per C element, fp32 single-accumulator fmaf chain, k ascending,
//     OpenBLAS kc=384 panel folds: C = ((P1 + P2) + P3) + bias, each +
//     a single __fadd_rn. Realized here as 3 launches:
//       P1: C = acc(k 0..383)
//       P2: C = fadd(C, acc(k 384..767))
//       P3: C = fadd(fadd(C, acc(k 768..783)), bias)
//     Bit-identical to the single-kernel tot/acc version.
//   * gemm2: f64 accumulation of fp32 products, +b2 in f64, single rounding.
//   * recurrences: fp32 _rn ops, ((0.95*mem + cur) - rst), no contraction;
//     spike/reset = (mem > 1.0f).
// PERF JOURNAL:
//   * R5 570us: 8x8 single-buf, VALUBusy 36%, latency-bound (2 waves/SIMD).
//   * R6 2144us: __launch_bounds__(256,3) clamped VGPR->84, scratch spill,
//     9.5 GB HBM. Never use min-waves arg near the register boundary.
//   * R7 453us: dbuf 8x4, VGPR 148, VALUBusy 38% — LDS-pipe bound:
//     3 b128/kk per 32 fma = 2.25x LDS oversubscription; also B-reads were
//     4-way bank conflicted (tn=(tid&15)*8 -> stride-8 banks).
//   * R8: 3-launch panel split kills tot[] regs -> 8x8 micro, BK=8,
//     8x8 lane grid (lm=(lane&7)*8, ln=(lane>>3)*8: all LDS reads <=2-way
//     = free). LDS:VALU = 0.75 -> VALU-bound.
// ===========================================================================

// ---------------------------------------------------------------------------
// GEMM1 panel kernel: 384 k-values starting at kb. BM=BN=128, BK=8,
// 256 threads = 4 waves in 2x2; each wave 8x8 lanes; micro 8x8.
// Double-buffered LDS, one barrier per iteration, prefetch-ahead.
// ---------------------------------------------------------------------------
#define BM 128
#define BN 128
#define BK 8
#define PANEL_K 384

template<bool ACC>
__global__ __launch_bounds__(256) void gemm1_panel(
    const float* __restrict__ X, const float* __restrict__ W,
    float* __restrict__ C, int kb)
{
    __shared__ float As[2][BK][BM + 4];   // 2 x 4224 B
    __shared__ float Bs[2][BK][BN + 4];   // 2 x 4224 B

    const int tid = threadIdx.x;
    const int bm  = blockIdx.x * BM;
    const int bn  = blockIdx.y * BN;

    // staging: 128 rows x 8 k = 256 float4
    const int row  = tid >> 1;           // 0..127
    const int koff = (tid & 1) * 4;      // 0 or 4

    // compute mapping: wave 2x2, lane 8x8, micro 8x8
    const int w    = tid >> 6;
    const int lane = tid & 63;
    const int tm   = (w & 1) * 64 + (lane & 7) * 8;    // 0..120
    const int tn   = (w >> 1) * 64 + (lane >> 3) * 8;  // 0..120

    float acc[8][8];
    #pragma unroll
    for (int i = 0; i < 8; ++i)
        #pragma unroll
        for (int j = 0; j < 8; ++j) acc[i][j] = 0.f;

    const float* Xp = X + (size_t)(bm + row) * NIN + kb + koff;
    const float* Wp = W + (size_t)(bn + row) * NIN + kb + koff;

    // prologue: stage iter 0 into buffer 0
    float4 pa = *(const float4*)(Xp);
    float4 pb = *(const float4*)(Wp);
    As[0][koff+0][row] = pa.x; As[0][koff+1][row] = pa.y;
    As[0][koff+2][row] = pa.z; As[0][koff+3][row] = pa.w;
    Bs[0][koff+0][row] = pb.x; Bs[0][koff+1][row] = pb.y;
    Bs[0][koff+2][row] = pb.z; Bs[0][koff+3][row] = pb.w;

    const int NITER = PANEL_K / BK;   // 48
    for (int it = 0; it < NITER; ++it) {
        const int cur = it & 1;
        __syncthreads();

        if (it + 1 < NITER) {
            const int k0 = (it + 1) * BK;
            pa = *(const float4*)(Xp + k0);
            pb = *(const float4*)(Wp + k0);
        }

        #pragma unroll
        for (int kk = 0; kk < BK; ++kk) {   // k ascending
            float4 av0 = *(const float4*)&As[cur][kk][tm];
            float4 av1 = *(const float4*)&As[cur][kk][tm + 4];
            float4 bv0 = *(const float4*)&Bs[cur][kk][tn];
            float4 bv1 = *(const float4*)&Bs[cur][kk][tn + 4];
            float a[8] = {av0.x, av0.y, av0.z, av0.w, av1.x, av1.y, av1.z, av1.w};
            float b[8] = {bv0.x, bv0.y, bv0.z, bv0.w, bv1.x, bv1.y, bv1.z, bv1.w};
            #pragma unroll
            for (int i = 0; i < 8; ++i)
                #pragma unroll
                for (int j = 0; j < 8; ++j)
                    acc[i][j] = fmaf(a[i], b[j], acc[i][j]);
        }

        if (it + 1 < NITER) {
            const int nxt = cur ^ 1;
            As[nxt][koff+0][row] = pa.x; As[nxt][koff+1][row] = pa.y;
            As[nxt][koff+2][row] = pa.z; As[nxt][koff+3][row] = pa.w;
            Bs[nxt][koff+0][row] = pb.x; Bs[nxt][koff+1][row] = pb.y;
            Bs[nxt][koff+2][row] = pb.z; Bs[nxt][koff+3][row] = pb.w;
        }
    }

    #pragma unroll
    for (int i = 0; i < 8; ++i) {
        size_t r = (size_t)(bm + tm + i) * NHID + bn + tn;
        float4 o0, o1;
        if (ACC) {
            float4 c0 = *(const float4*)&C[r];
            float4 c1 = *(const float4*)&C[r + 4];
            o0.x = __fadd_rn(c0.x, acc[i][0]); o0.y = __fadd_rn(c0.y, acc[i][1]);
            o0.z = __fadd_rn(c0.z, acc[i][2]); o0.w = __fadd_rn(c0.w, acc[i][3]);
            o1.x = __fadd_rn(c1.x, acc[i][4]); o1.y = __fadd_rn(c1.y, acc[i][5]);
            o1.z = __fadd_rn(c1.z, acc[i][6]); o1.w = __fadd_rn(c1.w, acc[i][7]);
        } else {
            o0 = make_float4(acc[i][0], acc[i][1], acc[i][2], acc[i][3]);
            o1 = make_float4(acc[i][4], acc[i][5], acc[i][6], acc[i][7]);
        }
        *(float4*)&C[r]     = o0;
        *(float4*)&C[r + 4] = o1;
    }
}

// ---------------------------------------------------------------------------
// GEMM1 tail (P3): 16 k-values (768..783) + bias, accumulated into C.
// Block 256 = 16x16 threads, each 4x4 micro; tile 64m x 64n.
// W tail slice staged in LDS k-major [16][68] (reads 2-way, free).
// ---------------------------------------------------------------------------
__global__ __launch_bounds__(256) void gemm1_tail(
    const float* __restrict__ X, const float* __restrict__ W,
    const float* __restrict__ bias, float* __restrict__ C)
{
    __shared__ float ws[16][68];
    const int tid = threadIdx.x;
    const int bm = blockIdx.x * 64;
    const int bn = blockIdx.y * 64;

    // stage W[bn..bn+63][768..783]: v -> nrow=v>>2, kq=v&3 (float4 along k)
    {
        const int nrow = tid >> 2, kq = (tid & 3) * 4;
        float4 wv = *(const float4*)&W[(size_t)(bn + nrow) * NIN + 768 + kq];
        ws[kq+0][nrow] = wv.x; ws[kq+1][nrow] = wv.y;
        ws[kq+2][nrow] = wv.z; ws[kq+3][nrow] = wv.w;
    }
    __syncthreads();

    const int tm = (tid >> 4) * 4;   // 0..60
    const int tn = (tid & 15) * 4;   // 0..60

    // X tail: 4 rows x 16 k into registers
    float xr[4][16];
    #pragma unroll
    for (int i = 0; i < 4; ++i)
        #pragma unroll
        for (int q = 0; q < 4; ++q) {
            float4 xv = *(const float4*)&X[(size_t)(bm + tm + i) * NIN + 768 + q * 4];
            xr[i][q*4+0] = xv.x; xr[i][q*4+1] = xv.y;
            xr[i][q*4+2] = xv.z; xr[i][q*4+3] = xv.w;
        }

    float acc[4][4];
    #pragma unroll
    for (int i = 0; i < 4; ++i)
        #pragma unroll
        for (int j = 0; j < 4; ++j) acc[i][j] = 0.f;

    #pragma unroll
    for (int kk = 0; kk < 16; ++kk) {   // k ascending
        float4 bv = *(const float4*)&ws[kk][tn];
        float b[4] = {bv.x, bv.y, bv.z, bv.w};
        #pragma unroll
        for (int i = 0; i < 4; ++i)
            #pragma unroll
            for (int j = 0; j < 4; ++j)
                acc[i][j] = fmaf(xr[i][kk], b[j], acc[i][j]);
    }

    float4 bi = *(const float4*)&bias[bn + tn];
    #pragma unroll
    for (int i = 0; i < 4; ++i) {
        size_t r = (size_t)(bm + tm + i) * NHID + bn + tn;
        float4 c = *(const float4*)&C[r];
        float4 o;
        o.x = __fadd_rn(__fadd_rn(c.x, acc[i][0]), bi.x);
        o.y = __fadd_rn(__fadd_rn(c.y, acc[i][1]), bi.y);
        o.z = __fadd_rn(__fadd_rn(c.z, acc[i][2]), bi.z);
        o.w = __fadd_rn(__fadd_rn(c.w, acc[i][3]), bi.w);
        *(float4*)&C[r] = o;
    }
}

// ---------------------------------------------------------------------------
// Hidden Leaky recurrence (fp32 _rn), scalar, depth-8 ring-buffer prefetch.
// 512 blocks x 256 threads = 131072 chains, fully resident. In place:
// mem_io holds cur1 on entry, mem1 on exit.
// ---------------------------------------------------------------------------
__global__ __launch_bounds__(256) void leaky_hidden_kernel(
    float* __restrict__ mem_io, float* __restrict__ spk_out)
{
    const int idx = blockIdx.x * blockDim.x + threadIdx.x;  // 0..131071
    const size_t STRIDE = (size_t)BATCH * NHID;

    float buf[8];
    #pragma unroll
    for (int i = 0; i < 8; ++i) buf[i] = mem_io[idx + (size_t)i * STRIDE];

    float mem = 0.f;
    #pragma unroll 4
    for (int t = 0; t < T_STEPS; ++t) {
        float cur = buf[t & 7];
        int tn = t + 8;
        if (tn < T_STEPS) buf[t & 7] = mem_io[idx + (size_t)tn * STRIDE];
        float rst = (mem > 1.0f) ? 1.0f : 0.0f;
        mem = __fsub_rn(__fadd_rn(__fmul_rn(0.95f, mem), cur), rst);
        size_t off = idx + (size_t)t * STRIDE;
        spk_out[off] = (mem > 1.0f) ? 1.0f : 0.0f;
        mem_io[off]  = mem;
    }
}

// ---------------------------------------------------------------------------
// GEMM2: cur2[m][o] = fl32( f64( sum_k spk1[m][k]*W2[o][k] + b2[o] ) )
// W2 (20 KB) staged in LDS. Block = 320 threads = 32 rows x 10 outputs.
// ---------------------------------------------------------------------------
#define G2_ROWS 32

__global__ __launch_bounds__(320) void gemm2_f64(
    const float* __restrict__ spk1, const float* __restrict__ W2,
    const float* __restrict__ b2, float* __restrict__ cur2)
{
    __shared__ float w2s[NOUT * NHID];  // 20 KB
    const int tid = threadIdx.x;
    for (int i = tid; i < NOUT * NHID; i += 320) w2s[i] = W2[i];
    __syncthreads();

    const int r = tid / NOUT;   // 0..31
    const int o = tid % NOUT;   // 0..9
    const size_t m = (size_t)blockIdx.x * G2_ROWS + r;
    const float* rowp = spk1 + m * NHID;
    const float* wp   = w2s + o * NHID;
    double dot = 0.0;
    #pragma unroll 4
    for (int k = 0; k < NHID; k += 4) {
        float4 s  = *(const float4*)(rowp + k);
        float4 wv = *(const float4*)(wp + k);
        dot = fma((double)s.x, (double)wv.x, dot);
        dot = fma((double)s.y, (double)wv.y, dot);
        dot = fma((double)s.z, (double)wv.z, dot);
        dot = fma((double)s.w, (double)wv.w, dot);
    }
    cur2[m * NOUT + o] = (float)(dot + (double)b2[o]);   // coalesced
}

// ---------------------------------------------------------------------------
// Output Leaky recurrence (fp32 _rn): one thread per (b,o) chain (2560).
// ---------------------------------------------------------------------------
__global__ __launch_bounds__(256) void leaky_out_kernel(
    const float* __restrict__ cur2, float* __restrict__ spk2,
    float* __restrict__ mem2)
{
    const int idx = blockIdx.x * blockDim.x + threadIdx.x;
    if (idx >= BATCH * NOUT) return;
    const int STRIDE = BATCH * NOUT;

    float buf[8];
    #pragma unroll
    for (int i = 0; i < 8; ++i) buf[i] = cur2[(size_t)i * STRIDE + idx];

    float mem = 0.f;
    #pragma unroll 4
    for (int t = 0; t < T_STEPS; ++t) {
        float cur = buf[t & 7];
        int tn = t + 8;
        if (tn < T_STEPS) buf[t & 7] = cur2[(size_t)tn * STRIDE + idx];
        float rst = (mem > 1.0f) ? 1.0f : 0.0f;
        mem = __fsub_rn(__fadd_rn(__fmul_rn(0.95f, mem), cur), rst);
        size_t off = (size_t)t * STRIDE + idx;
        spk2[off] = (mem > 1.0f) ? 1.0f : 0.0f;
        mem2[off] = mem;
    }
}

// ---------------------------------------------------------------------------
extern "C" void kernel_launch(void* const* d_in, const int* in_sizes, int n_in,
                              void* d_out, int out_size, void* d_ws, size_t ws_size,
                              hipStream_t stream) {
    const float* x  = (const float*)d_in[0];   // (100, 256, 784)
    const float* w1 = (const float*)d_in[1];   // (512, 784)
    const float* b1 = (const float*)d_in[2];   // (512,)
    const float* w2 = (const float*)d_in[3];   // (10, 512)
    const float* b2 = (const float*)d_in[4];   // (10,)

    float* out = (float*)d_out;
    // Output tuple order: (cur2, spk2, spk1, mem2, mem1), each stacked over T.
    float* cur2_out = out;                       // 256000
    float* spk2_out = out + 256000;              // 256000
    float* spk1_out = out + 512000;              // 13107200
    float* mem2_out = out + 13619200;            // 256000
    float* mem1_out = out + 13875200;            // 13107200

    const int M = T_STEPS * BATCH;               // 25600

    // 1) cur1 = X @ W1^T + b1 via 3 panel launches into the mem1 region.
    dim3 gp(M / BM, NHID / BN);                  // (200, 4)
    gemm1_panel<false><<<gp, 256, 0, stream>>>(x, w1, mem1_out, 0);
    gemm1_panel<true ><<<gp, 256, 0, stream>>>(x, w1, mem1_out, 384);
    dim3 gt(M / 64, NHID / 64);                  // (400, 8)
    gemm1_tail<<<gt, 256, 0, stream>>>(x, w1, b1, mem1_out);

    // 2) hidden Leaky chains (fp32 _rn, scalar ring-buffer):
    leaky_hidden_kernel<<<(BATCH * NHID) / 256, 256, 0, stream>>>(mem1_out, spk1_out);

    // 3) cur2 = spk1 @ W2^T + b2 (f64 acc -> fp32)
    gemm2_f64<<<M / G2_ROWS, 320, 0, stream>>>(spk1_out, w2, b2, cur2_out);

    // 4) output Leaky chains (fp32 _rn): cur2 -> (spk2, mem2)
    leaky_out_kernel<<<(BATCH * NOUT + 255) / 256, 256, 0, stream>>>(
        cur2_out, spk2_out, mem2_out);
}